// Round 1
// baseline (8168.993 us; speedup 1.0000x reference)
//
#include <hip/hip_runtime.h>
#include <math.h>

#define B_N   128
#define M_N   248
#define C_N   248
#define NODES 256
#define NBLK  8            // blocks per batch
#define RPB   31           // rows per block (8*31 = 248)
#define NG    (B_N*M_N*C_N)   // 7,872,512
#define NT    (B_N*NODES)     // 32,768

#define PI_F     3.14159265358979323846f
#define INV_BM   (1.0f/31744.0f)
#define INV_BMC  (1.0f/7872512.0f)

__device__ __forceinline__ float sigm(float x) {
    float z = expf(-fabsf(x));
    return (x >= 0.0f) ? 1.0f/(1.0f+z) : z/(1.0f+z);
}

__device__ __forceinline__ float sgn(float x) {
    return (x > 0.0f) ? 1.0f : ((x < 0.0f) ? -1.0f : 0.0f);
}

// One Adam iteration t (1..200).
// Prologue: apply T-update for step t-1 (from partials of iteration t-1).
// Main: grads at (G_{t-1}, T_{t-1}); Adam-update G in place; store T-grad partials.
// T/mT/vT state double-buffered: prologue reads slot t&1, writes (t+1)&1.
// gTu/gTv partials: prologue reads slot (t-1)&1, main writes slot t&1.
__global__ __launch_bounds__(256) void iter_kernel(
    const float* __restrict__ adj, float* __restrict__ Gl,
    float* __restrict__ mG, float* __restrict__ vG,
    float* __restrict__ T_state, float* __restrict__ mT, float* __restrict__ vT,
    float* __restrict__ gTu, float* __restrict__ gTv,
    int t, float bc1p, float bc2p, float bc1, float bc2)
{
    __shared__ float T_lds[NODES];
    __shared__ float gv_lds[4*NODES];
    const int tid = threadIdx.x;
    const int b   = blockIdx.x >> 3;
    const int blk = blockIdx.x & 7;

    // ---------- prologue ----------
    if (t == 1) {
        T_lds[tid] = T_state[b*NODES + tid];      // slot 0 holds T0
    } else {
        const int rs = t & 1, ws2 = (t+1) & 1, ps = (t-1) & 1;
        const int idx = b*NODES + tid;
        float Tval = T_state[rs*NT + idx];
        float g = 0.0f;
        if (tid < M_N) g += gTu[ps*(B_N*M_N) + b*M_N + tid];
        if (tid >= 8) {
            const float* gp = gTv + (size_t)ps*(B_N*NBLK*C_N) + (size_t)b*NBLK*C_N + (tid-8);
            float s = 0.0f;
            #pragma unroll
            for (int k = 0; k < NBLK; ++k) s += gp[k*C_N];
            g -= s;
        }
        g *= INV_BMC;
        float m_ = 0.9f*mT[rs*NT+idx] + 0.1f*g;
        float v_ = 0.999f*vT[rs*NT+idx] + 0.001f*(g*g);
        float newT = Tval - 0.1f*(m_/bc1p)/(sqrtf(v_/bc2p) + 1e-8f);
        T_state[ws2*NT+idx] = newT;   // 8 blocks/batch write identical values: benign
        mT[ws2*NT+idx] = m_;
        vT[ws2*NT+idx] = v_;
        T_lds[tid] = newT;
    }
    gv_lds[tid] = 0.0f; gv_lds[256+tid] = 0.0f; gv_lds[512+tid] = 0.0f; gv_lds[768+tid] = 0.0f;
    __syncthreads();

    // ---------- main ----------
    const int wave = tid >> 6, lane = tid & 63;
    const int pw = t & 1;
    const int j0 = lane, j1 = lane+64, j2 = lane+128, j3 = lane+192;
    const bool v3 = (lane < 56);
    float av0 = 0.0f, av1 = 0.0f, av2 = 0.0f, av3 = 0.0f;

    for (int r = wave; r < RPB; r += 4) {
        const int i = blk*RPB + r;                               // V_MEAS[i] = i
        const size_t arow = ((size_t)(b*NODES + i))*NODES + 8;   // V_CORR[j] = j+8
        const size_t grow = ((size_t)(b*M_N + i))*C_N;

        float gl0 = Gl[grow+j0], gl1 = Gl[grow+j1], gl2 = Gl[grow+j2];
        float gl3 = v3 ? Gl[grow+j3] : 0.0f;
        float a0 = adj[arow+j0], a1 = adj[arow+j1], a2 = adj[arow+j2];
        float a3 = v3 ? adj[arow+j3] : 0.0f;
        float G0 = sigm(gl0), G1 = sigm(gl1), G2 = sigm(gl2), G3 = sigm(gl3);

        float Tu = T_lds[i];
        float d0 = Tu - T_lds[j0+8] + 0.1f;
        float d1 = Tu - T_lds[j1+8] + 0.1f;
        float d2 = Tu - T_lds[j2+8] + 0.1f;
        float d3 = v3 ? (Tu - T_lds[j3+8] + 0.1f) : 0.0f;
        float p0 = fmaxf(d0, 0.0f), p1 = fmaxf(d1, 0.0f);
        float p2 = fmaxf(d2, 0.0f), p3 = fmaxf(d3, 0.0f);
        float mk0 = (d0 > 0.0f) ? 1.0f : 0.0f;
        float mk1 = (d1 > 0.0f) ? 1.0f : 0.0f;
        float mk2 = (d2 > 0.0f) ? 1.0f : 0.0f;
        float mk3 = (v3 && d3 > 0.0f) ? 1.0f : 0.0f;

        float sp = a0*G0 + a1*G1 + a2*G2 + (v3 ? a3*G3 : 0.0f);
        float gu = G0*mk0 + G1*mk1 + G2*mk2 + G3*mk3;
        #pragma unroll
        for (int off = 32; off > 0; off >>= 1) {
            sp += __shfl_xor(sp, off, 64);
            gu += __shfl_xor(gu, off, 64);
        }
        av0 += G0*mk0; av1 += G1*mk1; av2 += G2*mk2; av3 += G3*mk3;

        float half_arg = (PI_F*sp)*0.5f;
        float sv = sinf(half_arg), cv = cosf(half_arg);
        float val = sv*sv;
        float coefP = 2.0f*(val-1.0f)*sv*cv*PI_F*INV_BM;

        if (lane == 0) gTu[pw*(B_N*M_N) + b*M_N + i] = gu;   // raw sum; scaled at use

        #define DO_SLOT(Gx, glx, ax, px, jx, valid) do { if (valid) {            \
            float dG  = coefP*(ax) + (px)*INV_BMC + 0.1f*INV_BMC*sgn((Gx)-0.5f); \
            float grd = dG * (Gx) * (1.0f - (Gx));                               \
            float m_ = 0.9f*mG[grow+(jx)] + 0.1f*grd;                            \
            float v_ = 0.999f*vG[grow+(jx)] + 0.001f*(grd*grd);                  \
            mG[grow+(jx)] = m_; vG[grow+(jx)] = v_;                              \
            Gl[grow+(jx)] = (glx) - 0.1f*(m_/bc1)/(sqrtf(v_/bc2)+1e-8f);         \
        } } while (0)
        DO_SLOT(G0, gl0, a0, p0, j0, true);
        DO_SLOT(G1, gl1, a1, p1, j1, true);
        DO_SLOT(G2, gl2, a2, p2, j2, true);
        DO_SLOT(G3, gl3, a3, p3, j3, v3);
        #undef DO_SLOT
    }

    // grad_T_v column partials: per-wave LDS slices, deterministic cross-wave sum
    gv_lds[wave*256 + j0] = av0;
    gv_lds[wave*256 + j1] = av1;
    gv_lds[wave*256 + j2] = av2;
    if (v3) gv_lds[wave*256 + j3] = av3;
    __syncthreads();
    if (tid < C_N) {
        float s = gv_lds[tid] + gv_lds[256+tid] + gv_lds[512+tid] + gv_lds[768+tid];
        gTv[(size_t)pw*(B_N*NBLK*C_N) + (size_t)(b*NBLK + blk)*C_N + tid] = s;
    }
}

// Apply the step-200 T update (t=201 semantics: read slot 1, partials slot 0, write slot 0)
__global__ __launch_bounds__(256) void t_fin_kernel(
    float* __restrict__ T_state, const float* __restrict__ mT, const float* __restrict__ vT,
    const float* __restrict__ gTu, const float* __restrict__ gTv,
    float bc1p, float bc2p)
{
    const int b = blockIdx.x, tid = threadIdx.x;
    const int idx = b*NODES + tid;
    float Tval = T_state[1*NT + idx];
    float g = 0.0f;
    if (tid < M_N) g += gTu[0*(B_N*M_N) + b*M_N + tid];
    if (tid >= 8) {
        const float* gp = gTv + (size_t)b*NBLK*C_N + (tid-8);   // slot 0
        float s = 0.0f;
        #pragma unroll
        for (int k = 0; k < NBLK; ++k) s += gp[k*C_N];
        g -= s;
    }
    g *= INV_BMC;
    float m_ = 0.9f*mT[1*NT+idx] + 0.1f*g;
    float v_ = 0.999f*vT[1*NT+idx] + 0.001f*(g*g);
    T_state[0*NT+idx] = Tval - 0.1f*(m_/bc1p)/(sqrtf(v_/bc2p) + 1e-8f);
}

__global__ __launch_bounds__(256) void loss_kernel(
    const float* __restrict__ adj, const float* __restrict__ Gl,
    const float* __restrict__ T_state, float* __restrict__ accum)
{
    __shared__ float T_lds[NODES];
    __shared__ float red[8];
    const int tid = threadIdx.x;
    const int b = blockIdx.x >> 3, blk = blockIdx.x & 7;
    T_lds[tid] = T_state[b*NODES + tid];   // slot 0 = final T
    __syncthreads();
    const int wave = tid >> 6, lane = tid & 63;
    const int j0 = lane, j1 = lane+64, j2 = lane+128, j3 = lane+192;
    const bool v3 = (lane < 56);
    float pacc = 0.0f, cacc = 0.0f;

    for (int r = wave; r < RPB; r += 4) {
        const int i = blk*RPB + r;
        const size_t arow = ((size_t)(b*NODES + i))*NODES + 8;
        const size_t grow = ((size_t)(b*M_N + i))*C_N;
        float gl0 = Gl[grow+j0], gl1 = Gl[grow+j1], gl2 = Gl[grow+j2];
        float gl3 = v3 ? Gl[grow+j3] : 0.0f;
        float a0 = adj[arow+j0], a1 = adj[arow+j1], a2 = adj[arow+j2];
        float a3 = v3 ? adj[arow+j3] : 0.0f;
        float G0 = sigm(gl0), G1 = sigm(gl1), G2 = sigm(gl2), G3 = sigm(gl3);

        float Tu = T_lds[i];
        float p0 = fmaxf(Tu - T_lds[j0+8] + 0.1f, 0.0f);
        float p1 = fmaxf(Tu - T_lds[j1+8] + 0.1f, 0.0f);
        float p2 = fmaxf(Tu - T_lds[j2+8] + 0.1f, 0.0f);
        float p3 = v3 ? fmaxf(Tu - T_lds[j3+8] + 0.1f, 0.0f) : 0.0f;

        float sp = a0*G0 + a1*G1 + a2*G2 + (v3 ? a3*G3 : 0.0f);
        float cp = G0*p0 + G1*p1 + G2*p2 + (v3 ? G3*p3 : 0.0f);
        #pragma unroll
        for (int off = 32; off > 0; off >>= 1) {
            sp += __shfl_xor(sp, off, 64);
            cp += __shfl_xor(cp, off, 64);
        }
        if (lane == 0) {
            float sv = sinf((PI_F*sp)*0.5f);
            float dd = sv*sv - 1.0f;
            pacc += dd*dd;
            cacc += cp;
        }
    }
    if (lane == 0) { red[wave] = pacc; red[4+wave] = cacc; }
    __syncthreads();
    if (tid == 0) {
        atomicAdd(&accum[0], red[0]+red[1]+red[2]+red[3]);
        atomicAdd(&accum[1], red[4]+red[5]+red[6]+red[7]);
    }
}

__global__ void finish_kernel(const float* __restrict__ accum, float* __restrict__ out) {
    if (threadIdx.x == 0 && blockIdx.x == 0) {
        float p = accum[0] / 31744.0f;
        float c = accum[1] / 7872512.0f;
        out[0] = p + c;
        out[1] = p;
        out[2] = c;
    }
}

extern "C" void kernel_launch(void* const* d_in, const int* in_sizes, int n_in,
                              void* d_out, int out_size, void* d_ws, size_t ws_size,
                              hipStream_t stream) {
    const float* adj = (const float*)d_in[0];
    float* Gl        = (float*)d_in[1];        // updated in place (harness restores)
    const float* T0  = (const float*)d_in[2];
    float* out       = (float*)d_out;
    float* ws        = (float*)d_ws;

    float* mG      = ws;                       // NG
    float* vG      = mG + NG;                  // NG
    float* T_state = vG + NG;                  // 2*NT
    float* mT      = T_state + 2*NT;           // 2*NT
    float* vT      = mT + 2*NT;                // 2*NT
    float* gTu     = vT + 2*NT;                // 2*B*M
    float* gTv     = gTu + 2*B_N*M_N;          // 2*B*NBLK*C
    float* accum   = gTv + (size_t)2*B_N*NBLK*C_N;  // 2

    hipMemsetAsync(mG, 0, (size_t)2*NG*sizeof(float), stream);     // mG + vG
    hipMemsetAsync(mT, 0, (size_t)4*NT*sizeof(float), stream);     // mT + vT (both slots)
    hipMemsetAsync(accum, 0, 2*sizeof(float), stream);
    hipMemcpyAsync(T_state, T0, NT*sizeof(float), hipMemcpyDeviceToDevice, stream);

    for (int t = 1; t <= 200; ++t) {
        float bc1p = 1.0f - (float)pow(0.9,   (double)(t-1));
        float bc2p = 1.0f - (float)pow(0.999, (double)(t-1));
        float bc1  = 1.0f - (float)pow(0.9,   (double)t);
        float bc2  = 1.0f - (float)pow(0.999, (double)t);
        iter_kernel<<<dim3(B_N*NBLK), dim3(256), 0, stream>>>(
            adj, Gl, mG, vG, T_state, mT, vT, gTu, gTv, t, bc1p, bc2p, bc1, bc2);
    }
    {
        float bc1p = 1.0f - (float)pow(0.9,   200.0);
        float bc2p = 1.0f - (float)pow(0.999, 200.0);
        t_fin_kernel<<<dim3(B_N), dim3(256), 0, stream>>>(T_state, mT, vT, gTu, gTv, bc1p, bc2p);
    }
    loss_kernel<<<dim3(B_N*NBLK), dim3(256), 0, stream>>>(adj, Gl, T_state, accum);
    finish_kernel<<<1, 64, 0, stream>>>(accum, out);
}

// Round 3
// 8113.055 us; speedup vs baseline: 1.0069x; 1.0069x over previous
//
#include <hip/hip_runtime.h>
#include <hip/hip_cooperative_groups.h>
#include <math.h>

namespace cg = cooperative_groups;

#define B_N   128
#define M_N   248
#define C_N   248
#define NODES 256
#define NT    (B_N*NODES)     // 32,768
#define NG    (B_N*M_N*C_N)   // 7,872,512

#define GRID  256             // 1 block per CU -> co-residency guaranteed
#define TPB   512             // 8 waves
#define HROWS 124             // rows per block (half batch)
#define KMAX  16              // rows per wave: lr = wave + 8*k

#define PI_F     3.14159265358979323846f
#define INV_BM   (1.0f/31744.0f)
#define INV_BMC  (1.0f/7872512.0f)

__device__ __forceinline__ float sigm(float x) {
    float z = expf(-fabsf(x));
    return (x >= 0.0f) ? 1.0f/(1.0f+z) : z/(1.0f+z);
}
__device__ __forceinline__ float sgn(float x) {
    return (x > 0.0f) ? 1.0f : ((x < 0.0f) ? -1.0f : 0.0f);
}

// ===================== persistent cooperative path =====================
// 256 blocks x 512 threads (1 block/CU). G-state (Gl,m,v) in VGPRs
// (192/lane), T-state in LDS, adj streamed from L2 each iteration.
// Cross-block traffic per iteration: gTu row sums + per-wave gTv column
// partials, double-buffered by parity; one grid.sync per iteration.
__global__ __launch_bounds__(TPB, 2) void persist_kernel(
    const float* __restrict__ adj, const float* __restrict__ Gl0,
    const float* __restrict__ T0,
    float* __restrict__ gTu,    // [2][B_N][M_N]
    float* __restrict__ gTv,    // [2][GRID*8][256]
    float* __restrict__ accum,  // [2]
    float* __restrict__ out)    // [3]
{
    __shared__ float T_lds[NODES], mT_lds[NODES], vT_lds[NODES];
    __shared__ float red[16];

    cg::grid_group grid = cg::this_grid();
    const int tid  = threadIdx.x;
    const int blkI = blockIdx.x;
    const int b    = blkI >> 1;          // batch
    const int h    = blkI & 1;           // half (rows h*124 .. h*124+123)
    const int wave = tid >> 6, lane = tid & 63;
    const int j0 = lane, j1 = lane+64, j2 = lane+128, j3 = lane+192;
    const bool v3 = (lane < 56);

    if (tid < NODES) {
        T_lds[tid]  = T0[b*NODES + tid];
        mT_lds[tid] = 0.0f;
        vT_lds[tid] = 0.0f;
    }

    float Gr[KMAX][4], mGr[KMAX][4], vGr[KMAX][4];
    #pragma unroll
    for (int k = 0; k < KMAX; ++k) {
        #pragma unroll
        for (int s = 0; s < 4; ++s) { Gr[k][s]=0.0f; mGr[k][s]=0.0f; vGr[k][s]=0.0f; }
        const int lr = wave + 8*k;
        if (lr < HROWS) {
            const int i = h*HROWS + lr;
            const size_t grow = ((size_t)(b*M_N + i))*C_N;
            Gr[k][0] = Gl0[grow+j0];
            Gr[k][1] = Gl0[grow+j1];
            Gr[k][2] = Gl0[grow+j2];
            if (v3) Gr[k][3] = Gl0[grow+j3];
        }
    }
    __syncthreads();

    double pw1d = 1.0, pw2d = 1.0;   // 0.9^(t-1), 0.999^(t-1) in fp64 (matches host pow)
    #pragma unroll 1
    for (int t = 1; t <= 200; ++t) {
        const float bc1p = (float)(1.0 - pw1d), bc2p = (float)(1.0 - pw2d);
        pw1d *= 0.9; pw2d *= 0.999;
        const float bc1 = (float)(1.0 - pw1d), bc2 = (float)(1.0 - pw2d);
        const int pw = t & 1, ps = (t-1) & 1;

        if (t > 1) {                 // grid-uniform
            grid.sync();
            // T Adam update for step t-1 (redundant per block, deterministic)
            if (tid < NODES) {
                float g = 0.0f;
                if (tid < M_N) g += gTu[ps*(B_N*M_N) + b*M_N + tid];
                if (tid >= 8) {
                    const float* gp = gTv + (size_t)ps*(GRID*8*256)
                                    + (size_t)(b*16)*256 + (tid-8);
                    float s = 0.0f;
                    #pragma unroll
                    for (int p = 0; p < 16; ++p) s += gp[p*256];
                    g -= s;
                }
                g *= INV_BMC;
                float m_ = 0.9f*mT_lds[tid] + 0.1f*g;
                float v_ = 0.999f*vT_lds[tid] + 0.001f*(g*g);
                mT_lds[tid] = m_; vT_lds[tid] = v_;
                T_lds[tid] = T_lds[tid] - 0.1f*(m_/bc1p)/(sqrtf(v_/bc2p) + 1e-8f);
            }
            __syncthreads();
        }

        // ---- main: grads + Adam on G (registers) ----
        float av0 = 0.0f, av1 = 0.0f, av2 = 0.0f, av3 = 0.0f;
        #pragma unroll
        for (int k = 0; k < KMAX; ++k) {
            const int lr = wave + 8*k;       // wave-uniform guard
            if (lr < HROWS) {
                const int i = h*HROWS + lr;
                const size_t arow = ((size_t)(b*NODES + i))*NODES + 8;
                const float a0 = adj[arow+j0];
                const float a1 = adj[arow+j1];
                const float a2 = adj[arow+j2];
                const float a3 = v3 ? adj[arow+j3] : 0.0f;

                const float G0 = sigm(Gr[k][0]), G1 = sigm(Gr[k][1]);
                const float G2 = sigm(Gr[k][2]), G3 = sigm(Gr[k][3]);

                const float Tu = T_lds[i];
                const float d0 = Tu - T_lds[j0+8] + 0.1f;
                const float d1 = Tu - T_lds[j1+8] + 0.1f;
                const float d2 = Tu - T_lds[j2+8] + 0.1f;
                const float d3 = v3 ? (Tu - T_lds[j3+8] + 0.1f) : 0.0f;
                const float p0 = fmaxf(d0,0.0f), p1 = fmaxf(d1,0.0f);
                const float p2 = fmaxf(d2,0.0f), p3 = fmaxf(d3,0.0f);
                const float mk0 = (d0>0.0f)?1.0f:0.0f;
                const float mk1 = (d1>0.0f)?1.0f:0.0f;
                const float mk2 = (d2>0.0f)?1.0f:0.0f;
                const float mk3 = (v3 && d3>0.0f)?1.0f:0.0f;

                float sp = a0*G0 + a1*G1 + a2*G2 + (v3 ? a3*G3 : 0.0f);
                float gu = G0*mk0 + G1*mk1 + G2*mk2 + G3*mk3;
                #pragma unroll
                for (int off = 32; off > 0; off >>= 1) {
                    sp += __shfl_xor(sp, off, 64);
                    gu += __shfl_xor(gu, off, 64);
                }
                av0 += G0*mk0; av1 += G1*mk1; av2 += G2*mk2; av3 += G3*mk3;

                const float half_arg = (PI_F*sp)*0.5f;
                const float sv = sinf(half_arg), cv = cosf(half_arg);
                const float coefP = 2.0f*(sv*sv-1.0f)*sv*cv*PI_F*INV_BM;

                if (lane == 0) gTu[pw*(B_N*M_N) + b*M_N + i] = gu;

                #define DO_SLOT(Gx, ax, px, s_, valid) do { if (valid) {                 \
                    float dG  = coefP*(ax) + (px)*INV_BMC + 0.1f*INV_BMC*sgn((Gx)-0.5f); \
                    float grd = dG * (Gx) * (1.0f - (Gx));                               \
                    float m_ = 0.9f*mGr[k][s_] + 0.1f*grd;                               \
                    float v_ = 0.999f*vGr[k][s_] + 0.001f*(grd*grd);                     \
                    mGr[k][s_] = m_; vGr[k][s_] = v_;                                    \
                    Gr[k][s_] = Gr[k][s_] - 0.1f*(m_/bc1)/(sqrtf(v_/bc2)+1e-8f);         \
                } } while (0)
                DO_SLOT(G0, a0, p0, 0, true);
                DO_SLOT(G1, a1, p1, 1, true);
                DO_SLOT(G2, a2, p2, 2, true);
                DO_SLOT(G3, a3, p3, 3, v3);
                #undef DO_SLOT
            }
        }
        // per-wave gTv column-partial slice
        {
            float* gpw = gTv + (size_t)pw*(GRID*8*256) + (size_t)(blkI*8 + wave)*256;
            gpw[j0] = av0; gpw[j1] = av1; gpw[j2] = av2; gpw[j3] = av3;
        }
    }

    // ---------------- final T update (step 200; slot 200&1 = 0) ----------------
    grid.sync();
    if (tid < NODES) {
        const float bc1p = (float)(1.0 - pw1d), bc2p = (float)(1.0 - pw2d);
        float g = 0.0f;
        if (tid < M_N) g += gTu[0*(B_N*M_N) + b*M_N + tid];
        if (tid >= 8) {
            const float* gp = gTv + (size_t)(b*16)*256 + (tid-8);
            float s = 0.0f;
            #pragma unroll
            for (int p = 0; p < 16; ++p) s += gp[p*256];
            g -= s;
        }
        g *= INV_BMC;
        float m_ = 0.9f*mT_lds[tid] + 0.1f*g;
        float v_ = 0.999f*vT_lds[tid] + 0.001f*(g*g);
        T_lds[tid] = T_lds[tid] - 0.1f*(m_/bc1p)/(sqrtf(v_/bc2p) + 1e-8f);
    }
    __syncthreads();

    // ---------------- final losses ----------------
    float pacc = 0.0f, cacc = 0.0f;
    #pragma unroll
    for (int k = 0; k < KMAX; ++k) {
        const int lr = wave + 8*k;
        if (lr < HROWS) {
            const int i = h*HROWS + lr;
            const size_t arow = ((size_t)(b*NODES + i))*NODES + 8;
            const float a0 = adj[arow+j0];
            const float a1 = adj[arow+j1];
            const float a2 = adj[arow+j2];
            const float a3 = v3 ? adj[arow+j3] : 0.0f;
            const float G0 = sigm(Gr[k][0]), G1 = sigm(Gr[k][1]);
            const float G2 = sigm(Gr[k][2]), G3 = sigm(Gr[k][3]);
            const float Tu = T_lds[i];
            const float p0 = fmaxf(Tu - T_lds[j0+8] + 0.1f, 0.0f);
            const float p1 = fmaxf(Tu - T_lds[j1+8] + 0.1f, 0.0f);
            const float p2 = fmaxf(Tu - T_lds[j2+8] + 0.1f, 0.0f);
            const float p3 = v3 ? fmaxf(Tu - T_lds[j3+8] + 0.1f, 0.0f) : 0.0f;

            float sp = a0*G0 + a1*G1 + a2*G2 + (v3 ? a3*G3 : 0.0f);
            float cp = G0*p0 + G1*p1 + G2*p2 + (v3 ? G3*p3 : 0.0f);
            #pragma unroll
            for (int off = 32; off > 0; off >>= 1) {
                sp += __shfl_xor(sp, off, 64);
                cp += __shfl_xor(cp, off, 64);
            }
            if (lane == 0) {
                const float sv = sinf((PI_F*sp)*0.5f);
                const float dd = sv*sv - 1.0f;
                pacc += dd*dd;
                cacc += cp;
            }
        }
    }
    if (lane == 0) { red[wave] = pacc; red[8+wave] = cacc; }
    __syncthreads();
    if (tid == 0) {
        float rp = 0.0f, rc = 0.0f;
        #pragma unroll
        for (int w = 0; w < 8; ++w) { rp += red[w]; rc += red[8+w]; }
        atomicAdd(&accum[0], rp);
        atomicAdd(&accum[1], rc);
    }
    __threadfence();
    grid.sync();
    if (blkI == 0 && tid == 0) {
        const float p = __hip_atomic_load(&accum[0], __ATOMIC_RELAXED, __HIP_MEMORY_SCOPE_AGENT) * INV_BM;
        const float c = __hip_atomic_load(&accum[1], __ATOMIC_RELAXED, __HIP_MEMORY_SCOPE_AGENT) * INV_BMC;
        out[0] = p + c;
        out[1] = p;
        out[2] = c;
    }
}

// ===================== fallback multi-launch path (round-1, known-good) =====================
#define NBLK  8
#define RPB   31

__global__ __launch_bounds__(256) void iter_kernel(
    const float* __restrict__ adj, float* __restrict__ Gl,
    float* __restrict__ mG, float* __restrict__ vG,
    float* __restrict__ T_state, float* __restrict__ mT, float* __restrict__ vT,
    float* __restrict__ gTu, float* __restrict__ gTv,
    int t, float bc1p, float bc2p, float bc1, float bc2)
{
    __shared__ float T_lds[NODES];
    __shared__ float gv_lds[4*NODES];
    const int tid = threadIdx.x;
    const int b   = blockIdx.x >> 3;
    const int blk = blockIdx.x & 7;

    if (t == 1) {
        T_lds[tid] = T_state[b*NODES + tid];
    } else {
        const int rs = t & 1, ws2 = (t+1) & 1, ps = (t-1) & 1;
        const int idx = b*NODES + tid;
        float Tval = T_state[rs*NT + idx];
        float g = 0.0f;
        if (tid < M_N) g += gTu[ps*(B_N*M_N) + b*M_N + tid];
        if (tid >= 8) {
            const float* gp = gTv + (size_t)ps*(B_N*NBLK*C_N) + (size_t)b*NBLK*C_N + (tid-8);
            float s = 0.0f;
            #pragma unroll
            for (int k = 0; k < NBLK; ++k) s += gp[k*C_N];
            g -= s;
        }
        g *= INV_BMC;
        float m_ = 0.9f*mT[rs*NT+idx] + 0.1f*g;
        float v_ = 0.999f*vT[rs*NT+idx] + 0.001f*(g*g);
        float newT = Tval - 0.1f*(m_/bc1p)/(sqrtf(v_/bc2p) + 1e-8f);
        T_state[ws2*NT+idx] = newT;
        mT[ws2*NT+idx] = m_;
        vT[ws2*NT+idx] = v_;
        T_lds[tid] = newT;
    }
    gv_lds[tid] = 0.0f; gv_lds[256+tid] = 0.0f; gv_lds[512+tid] = 0.0f; gv_lds[768+tid] = 0.0f;
    __syncthreads();

    const int wave = tid >> 6, lane = tid & 63;
    const int pw = t & 1;
    const int j0 = lane, j1 = lane+64, j2 = lane+128, j3 = lane+192;
    const bool v3 = (lane < 56);
    float av0 = 0.0f, av1 = 0.0f, av2 = 0.0f, av3 = 0.0f;

    for (int r = wave; r < RPB; r += 4) {
        const int i = blk*RPB + r;
        const size_t arow = ((size_t)(b*NODES + i))*NODES + 8;
        const size_t grow = ((size_t)(b*M_N + i))*C_N;

        float gl0 = Gl[grow+j0], gl1 = Gl[grow+j1], gl2 = Gl[grow+j2];
        float gl3 = v3 ? Gl[grow+j3] : 0.0f;
        float a0 = adj[arow+j0], a1 = adj[arow+j1], a2 = adj[arow+j2];
        float a3 = v3 ? adj[arow+j3] : 0.0f;
        float G0 = sigm(gl0), G1 = sigm(gl1), G2 = sigm(gl2), G3 = sigm(gl3);

        float Tu = T_lds[i];
        float d0 = Tu - T_lds[j0+8] + 0.1f;
        float d1 = Tu - T_lds[j1+8] + 0.1f;
        float d2 = Tu - T_lds[j2+8] + 0.1f;
        float d3 = v3 ? (Tu - T_lds[j3+8] + 0.1f) : 0.0f;
        float p0 = fmaxf(d0, 0.0f), p1 = fmaxf(d1, 0.0f);
        float p2 = fmaxf(d2, 0.0f), p3 = fmaxf(d3, 0.0f);
        float mk0 = (d0 > 0.0f) ? 1.0f : 0.0f;
        float mk1 = (d1 > 0.0f) ? 1.0f : 0.0f;
        float mk2 = (d2 > 0.0f) ? 1.0f : 0.0f;
        float mk3 = (v3 && d3 > 0.0f) ? 1.0f : 0.0f;

        float sp = a0*G0 + a1*G1 + a2*G2 + (v3 ? a3*G3 : 0.0f);
        float gu = G0*mk0 + G1*mk1 + G2*mk2 + G3*mk3;
        #pragma unroll
        for (int off = 32; off > 0; off >>= 1) {
            sp += __shfl_xor(sp, off, 64);
            gu += __shfl_xor(gu, off, 64);
        }
        av0 += G0*mk0; av1 += G1*mk1; av2 += G2*mk2; av3 += G3*mk3;

        float half_arg = (PI_F*sp)*0.5f;
        float sv = sinf(half_arg), cv = cosf(half_arg);
        float val = sv*sv;
        float coefP = 2.0f*(val-1.0f)*sv*cv*PI_F*INV_BM;

        if (lane == 0) gTu[pw*(B_N*M_N) + b*M_N + i] = gu;

        #define DO_SLOT(Gx, glx, ax, px, jx, valid) do { if (valid) {            \
            float dG  = coefP*(ax) + (px)*INV_BMC + 0.1f*INV_BMC*sgn((Gx)-0.5f); \
            float grd = dG * (Gx) * (1.0f - (Gx));                               \
            float m_ = 0.9f*mG[grow+(jx)] + 0.1f*grd;                            \
            float v_ = 0.999f*vG[grow+(jx)] + 0.001f*(grd*grd);                  \
            mG[grow+(jx)] = m_; vG[grow+(jx)] = v_;                              \
            Gl[grow+(jx)] = (glx) - 0.1f*(m_/bc1)/(sqrtf(v_/bc2)+1e-8f);         \
        } } while (0)
        DO_SLOT(G0, gl0, a0, p0, j0, true);
        DO_SLOT(G1, gl1, a1, p1, j1, true);
        DO_SLOT(G2, gl2, a2, p2, j2, true);
        DO_SLOT(G3, gl3, a3, p3, j3, v3);
        #undef DO_SLOT
    }

    gv_lds[wave*256 + j0] = av0;
    gv_lds[wave*256 + j1] = av1;
    gv_lds[wave*256 + j2] = av2;
    if (v3) gv_lds[wave*256 + j3] = av3;
    __syncthreads();
    if (tid < C_N) {
        float s = gv_lds[tid] + gv_lds[256+tid] + gv_lds[512+tid] + gv_lds[768+tid];
        gTv[(size_t)pw*(B_N*NBLK*C_N) + (size_t)(b*NBLK + blk)*C_N + tid] = s;
    }
}

__global__ __launch_bounds__(256) void t_fin_kernel(
    float* __restrict__ T_state, const float* __restrict__ mT, const float* __restrict__ vT,
    const float* __restrict__ gTu, const float* __restrict__ gTv,
    float bc1p, float bc2p)
{
    const int b = blockIdx.x, tid = threadIdx.x;
    const int idx = b*NODES + tid;
    float Tval = T_state[1*NT + idx];
    float g = 0.0f;
    if (tid < M_N) g += gTu[0*(B_N*M_N) + b*M_N + tid];
    if (tid >= 8) {
        const float* gp = gTv + (size_t)b*NBLK*C_N + (tid-8);
        float s = 0.0f;
        #pragma unroll
        for (int k = 0; k < NBLK; ++k) s += gp[k*C_N];
        g -= s;
    }
    g *= INV_BMC;
    float m_ = 0.9f*mT[1*NT+idx] + 0.1f*g;
    float v_ = 0.999f*vT[1*NT+idx] + 0.001f*(g*g);
    T_state[0*NT+idx] = Tval - 0.1f*(m_/bc1p)/(sqrtf(v_/bc2p) + 1e-8f);
}

__global__ __launch_bounds__(256) void loss_kernel(
    const float* __restrict__ adj, const float* __restrict__ Gl,
    const float* __restrict__ T_state, float* __restrict__ accum)
{
    __shared__ float T_lds[NODES];
    __shared__ float red[8];
    const int tid = threadIdx.x;
    const int b = blockIdx.x >> 3, blk = blockIdx.x & 7;
    T_lds[tid] = T_state[b*NODES + tid];
    __syncthreads();
    const int wave = tid >> 6, lane = tid & 63;
    const int j0 = lane, j1 = lane+64, j2 = lane+128, j3 = lane+192;
    const bool v3 = (lane < 56);
    float pacc = 0.0f, cacc = 0.0f;

    for (int r = wave; r < RPB; r += 4) {
        const int i = blk*RPB + r;
        const size_t arow = ((size_t)(b*NODES + i))*NODES + 8;
        const size_t grow = ((size_t)(b*M_N + i))*C_N;
        float gl0 = Gl[grow+j0], gl1 = Gl[grow+j1], gl2 = Gl[grow+j2];
        float gl3 = v3 ? Gl[grow+j3] : 0.0f;
        float a0 = adj[arow+j0], a1 = adj[arow+j1], a2 = adj[arow+j2];
        float a3 = v3 ? adj[arow+j3] : 0.0f;
        float G0 = sigm(gl0), G1 = sigm(gl1), G2 = sigm(gl2), G3 = sigm(gl3);

        float Tu = T_lds[i];
        float p0 = fmaxf(Tu - T_lds[j0+8] + 0.1f, 0.0f);
        float p1 = fmaxf(Tu - T_lds[j1+8] + 0.1f, 0.0f);
        float p2 = fmaxf(Tu - T_lds[j2+8] + 0.1f, 0.0f);
        float p3 = v3 ? fmaxf(Tu - T_lds[j3+8] + 0.1f, 0.0f) : 0.0f;

        float sp = a0*G0 + a1*G1 + a2*G2 + (v3 ? a3*G3 : 0.0f);
        float cp = G0*p0 + G1*p1 + G2*p2 + (v3 ? G3*p3 : 0.0f);
        #pragma unroll
        for (int off = 32; off > 0; off >>= 1) {
            sp += __shfl_xor(sp, off, 64);
            cp += __shfl_xor(cp, off, 64);
        }
        if (lane == 0) {
            float sv = sinf((PI_F*sp)*0.5f);
            float dd = sv*sv - 1.0f;
            pacc += dd*dd;
            cacc += cp;
        }
    }
    if (lane == 0) { red[wave] = pacc; red[4+wave] = cacc; }
    __syncthreads();
    if (tid == 0) {
        atomicAdd(&accum[0], red[0]+red[1]+red[2]+red[3]);
        atomicAdd(&accum[1], red[4]+red[5]+red[6]+red[7]);
    }
}

__global__ void finish_kernel(const float* __restrict__ accum, float* __restrict__ out) {
    if (threadIdx.x == 0 && blockIdx.x == 0) {
        float p = accum[0] / 31744.0f;
        float c = accum[1] / 7872512.0f;
        out[0] = p + c;
        out[1] = p;
        out[2] = c;
    }
}

extern "C" void kernel_launch(void* const* d_in, const int* in_sizes, int n_in,
                              void* d_out, int out_size, void* d_ws, size_t ws_size,
                              hipStream_t stream) {
    const float* adj = (const float*)d_in[0];
    float* Gl        = (float*)d_in[1];
    const float* T0  = (const float*)d_in[2];
    float* out       = (float*)d_out;
    float* ws        = (float*)d_ws;

    // deterministic host-side co-residency gate (pure host queries, capture-safe)
    int dev = 0;  hipGetDevice(&dev);
    int numCU = 0;
    hipDeviceGetAttribute(&numCU, hipDeviceAttributeMultiprocessorCount, dev);
    int maxB = 0;
    hipOccupancyMaxActiveBlocksPerMultiprocessor(&maxB, persist_kernel, TPB, 0);
    const bool coop_ok = (maxB >= 1) && ((long)maxB * (long)numCU >= GRID);

    if (coop_ok) {
        float* gTu   = ws;                               // 2*128*248
        float* gTv   = gTu + 2*B_N*M_N;                  // 2*GRID*8*256
        float* accum = gTv + (size_t)2*GRID*8*256;       // 2
        hipMemsetAsync(accum, 0, 2*sizeof(float), stream);

        const float* Gl0 = Gl;
        void* args[] = { (void*)&adj, (void*)&Gl0, (void*)&T0,
                         (void*)&gTu, (void*)&gTv, (void*)&accum, (void*)&out };
        hipLaunchCooperativeKernel((void*)persist_kernel,
                                   dim3(GRID), dim3(TPB), args, 0, stream);
    } else {
        float* mG      = ws;
        float* vG      = mG + NG;
        float* T_state = vG + NG;
        float* mT      = T_state + 2*NT;
        float* vT      = mT + 2*NT;
        float* gTu     = vT + 2*NT;
        float* gTv     = gTu + 2*B_N*M_N;
        float* accum   = gTv + (size_t)2*B_N*NBLK*C_N;

        hipMemsetAsync(mG, 0, (size_t)2*NG*sizeof(float), stream);
        hipMemsetAsync(mT, 0, (size_t)4*NT*sizeof(float), stream);
        hipMemsetAsync(accum, 0, 2*sizeof(float), stream);
        hipMemcpyAsync(T_state, T0, NT*sizeof(float), hipMemcpyDeviceToDevice, stream);

        for (int t = 1; t <= 200; ++t) {
            float bc1p = 1.0f - (float)pow(0.9,   (double)(t-1));
            float bc2p = 1.0f - (float)pow(0.999, (double)(t-1));
            float bc1  = 1.0f - (float)pow(0.9,   (double)t);
            float bc2  = 1.0f - (float)pow(0.999, (double)t);
            iter_kernel<<<dim3(B_N*NBLK), dim3(256), 0, stream>>>(
                adj, Gl, mG, vG, T_state, mT, vT, gTu, gTv, t, bc1p, bc2p, bc1, bc2);
        }
        {
            float bc1p = 1.0f - (float)pow(0.9,   200.0);
            float bc2p = 1.0f - (float)pow(0.999, 200.0);
            t_fin_kernel<<<dim3(B_N), dim3(256), 0, stream>>>(T_state, mT, vT, gTu, gTv, bc1p, bc2p);
        }
        loss_kernel<<<dim3(B_N*NBLK), dim3(256), 0, stream>>>(adj, Gl, T_state, accum);
        finish_kernel<<<1, 64, 0, stream>>>(accum, out);
    }
}